// Round 1
// baseline (138.710 us; speedup 1.0000x reference)
//
#include <hip/hip_runtime.h>

// Problem constants (from reference): B=8, C=256, K=64, T=1000
constexpr int Bn = 8;
constexpr int Cn = 256;
constexpr int Kn = 64;
constexpr int Tn = 1000;
constexpr int TT = 32;   // t-tile per block in weights kernel

// ---------------------------------------------------------------------------
// Kernel A: compute softmax weights w[b,k,t] over k.
//   r2[b,k,t] = sum_c (x[b,c,t] - codes[c,k])^2
//   w[b,k,t]  = softmax_k(-scales[k] * r2[b,k,t])
// Grid: B * 32 tiles (t-tiles of 32). Block: 256 threads = 4 waves.
// lane = k (64 codes = 64 lanes); each wave owns 8 t values of the tile.
// ---------------------------------------------------------------------------
__global__ __launch_bounds__(256) void lde_weights(
    const float* __restrict__ x,       // (B, C, T)
    const float* __restrict__ codes,   // (C, K)
    const float* __restrict__ scales,  // (K)
    float* __restrict__ w_out)         // (B, K, T)
{
    __shared__ float xs[64 * TT];   // [ci][tj], c-chunk of 64
    __shared__ float cs[64 * 64];   // [ci][k]

    const int tid  = threadIdx.x;
    const int wave = tid >> 6;
    const int lane = tid & 63;
    const int b    = blockIdx.x >> 5;        // 32 t-tiles per b
    const int t0   = (blockIdx.x & 31) * TT;

    float acc[8];
#pragma unroll
    for (int j = 0; j < 8; ++j) acc[j] = 0.f;

    const float sc = scales[lane];

    for (int c0 = 0; c0 < Cn; c0 += 64) {
        // stage codes chunk: contiguous 4096-float copy (coalesced)
#pragma unroll
        for (int r = 0; r < 16; ++r) {
            int i = tid + r * 256;
            cs[i] = codes[c0 * Kn + i];   // codes[(c0+ci)*K + k]
        }
        // stage x chunk: 64 rows x 32 t (coalesced over t, guarded at T edge)
        {
            const int tj = tid & 31;
            const int cb = tid >> 5;   // 0..7
            const int t  = t0 + tj;
#pragma unroll
            for (int r = 0; r < 8; ++r) {
                int ci = cb + r * 8;
                xs[ci * TT + tj] = (t < Tn) ? x[(b * Cn + c0 + ci) * Tn + t] : 0.f;
            }
        }
        __syncthreads();

#pragma unroll 2
        for (int c = 0; c < 64; ++c) {
            float cv = cs[c * 64 + lane];                      // conflict-free (2 lanes/bank)
            const float4* xr = (const float4*)(xs + c * TT + wave * 8);  // broadcast reads
            float4 xa = xr[0];
            float4 xb = xr[1];
            float d;
            d = xa.x - cv; acc[0] = fmaf(d, d, acc[0]);
            d = xa.y - cv; acc[1] = fmaf(d, d, acc[1]);
            d = xa.z - cv; acc[2] = fmaf(d, d, acc[2]);
            d = xa.w - cv; acc[3] = fmaf(d, d, acc[3]);
            d = xb.x - cv; acc[4] = fmaf(d, d, acc[4]);
            d = xb.y - cv; acc[5] = fmaf(d, d, acc[5]);
            d = xb.z - cv; acc[6] = fmaf(d, d, acc[6]);
            d = xb.w - cv; acc[7] = fmaf(d, d, acc[7]);
        }
        __syncthreads();
    }

    // softmax over k (= lanes) for each of this wave's 8 t's
#pragma unroll
    for (int j = 0; j < 8; ++j) {
        float logit = -sc * acc[j];
        float m = logit;
#pragma unroll
        for (int off = 32; off >= 1; off >>= 1)
            m = fmaxf(m, __shfl_xor(m, off, 64));
        float e = __expf(logit - m);
        float s = e;
#pragma unroll
        for (int off = 32; off >= 1; off >>= 1)
            s += __shfl_xor(s, off, 64);
        acc[j] = e / s;
    }

    const int tw = t0 + wave * 8;
    float* dst = w_out + (b * Kn + lane) * Tn + tw;
    if (tw + 7 < Tn) {
        // 4000-byte row stride and tw multiple of 8 -> 16B aligned
        ((float4*)dst)[0] = make_float4(acc[0], acc[1], acc[2], acc[3]);
        ((float4*)dst)[1] = make_float4(acc[4], acc[5], acc[6], acc[7]);
    } else {
#pragma unroll
        for (int j = 0; j < 8; ++j)
            if (tw + j < Tn) dst[j] = acc[j];
    }
}

// ---------------------------------------------------------------------------
// Kernel B: embeddings.
//   Xw[b,k,c] = sum_t x[b,c,t] * w[b,k,t];  S[b,k] = sum_t w[b,k,t]
//   E[b,k,c]  = (Xw - codes[c,k]*S) / T ;  out = E / max(||E||_c, eps)
// Grid: B * 16 (k-groups of 4). Block: 256 threads, thread = c.
// w-row reads are wave-uniform -> scalar-cache loads; x reads are float4.
// ---------------------------------------------------------------------------
__global__ __launch_bounds__(256) void lde_pool(
    const float* __restrict__ x,       // (B, C, T)
    const float* __restrict__ codes,   // (C, K)
    const float* __restrict__ w,       // (B, K, T)
    float* __restrict__ out)           // (B, K, C)
{
    const int tid  = threadIdx.x;
    const int wave = tid >> 6;
    const int lane = tid & 63;
    const int b    = blockIdx.x >> 4;
    const int k0   = (blockIdx.x & 15) * 4;

    __shared__ float S_s[4];
    __shared__ float ps[4][4];   // [kk][wave] partial sums of E^2

    // S[kk]: wave `wave` reduces row k0+wave
    {
        const float* wr = w + (b * Kn + k0 + wave) * Tn;
        float s = 0.f;
        for (int t = lane; t < Tn; t += 64) s += wr[t];
#pragma unroll
        for (int off = 32; off >= 1; off >>= 1) s += __shfl_xor(s, off, 64);
        if (lane == 0) S_s[wave] = s;
    }
    __syncthreads();

    const int c = tid;
    const float4* xr  = (const float4*)(x + (b * Cn + c) * Tn);
    const float4* wr0 = (const float4*)(w + (b * Kn + k0 + 0) * Tn);
    const float4* wr1 = (const float4*)(w + (b * Kn + k0 + 1) * Tn);
    const float4* wr2 = (const float4*)(w + (b * Kn + k0 + 2) * Tn);
    const float4* wr3 = (const float4*)(w + (b * Kn + k0 + 3) * Tn);

    float a0 = 0.f, a1 = 0.f, a2 = 0.f, a3 = 0.f;
#pragma unroll 2
    for (int i = 0; i < Tn / 4; ++i) {
        float4 xv = xr[i];
        float4 v;
        v = wr0[i]; a0 += xv.x * v.x + xv.y * v.y + xv.z * v.z + xv.w * v.w;
        v = wr1[i]; a1 += xv.x * v.x + xv.y * v.y + xv.z * v.z + xv.w * v.w;
        v = wr2[i]; a2 += xv.x * v.x + xv.y * v.y + xv.z * v.z + xv.w * v.w;
        v = wr3[i]; a3 += xv.x * v.x + xv.y * v.y + xv.z * v.z + xv.w * v.w;
    }

    const float invT = 1.0f / (float)Tn;
    float e0 = (a0 - codes[c * Kn + k0 + 0] * S_s[0]) * invT;
    float e1 = (a1 - codes[c * Kn + k0 + 1] * S_s[1]) * invT;
    float e2 = (a2 - codes[c * Kn + k0 + 2] * S_s[2]) * invT;
    float e3 = (a3 - codes[c * Kn + k0 + 3] * S_s[3]) * invT;

    // per-k L2 norm over c: wave-reduce then cross-wave via LDS
    float q;
    q = e0 * e0;
#pragma unroll
    for (int off = 32; off >= 1; off >>= 1) q += __shfl_xor(q, off, 64);
    if (lane == 0) ps[0][wave] = q;
    q = e1 * e1;
#pragma unroll
    for (int off = 32; off >= 1; off >>= 1) q += __shfl_xor(q, off, 64);
    if (lane == 0) ps[1][wave] = q;
    q = e2 * e2;
#pragma unroll
    for (int off = 32; off >= 1; off >>= 1) q += __shfl_xor(q, off, 64);
    if (lane == 0) ps[2][wave] = q;
    q = e3 * e3;
#pragma unroll
    for (int off = 32; off >= 1; off >>= 1) q += __shfl_xor(q, off, 64);
    if (lane == 0) ps[3][wave] = q;
    __syncthreads();

    float n0 = sqrtf(ps[0][0] + ps[0][1] + ps[0][2] + ps[0][3]);
    float n1 = sqrtf(ps[1][0] + ps[1][1] + ps[1][2] + ps[1][3]);
    float n2 = sqrtf(ps[2][0] + ps[2][1] + ps[2][2] + ps[2][3]);
    float n3 = sqrtf(ps[3][0] + ps[3][1] + ps[3][2] + ps[3][3]);

    out[(b * Kn + k0 + 0) * Cn + c] = e0 / fmaxf(n0, 1e-12f);
    out[(b * Kn + k0 + 1) * Cn + c] = e1 / fmaxf(n1, 1e-12f);
    out[(b * Kn + k0 + 2) * Cn + c] = e2 / fmaxf(n2, 1e-12f);
    out[(b * Kn + k0 + 3) * Cn + c] = e3 / fmaxf(n3, 1e-12f);
}

extern "C" void kernel_launch(void* const* d_in, const int* in_sizes, int n_in,
                              void* d_out, int out_size, void* d_ws, size_t ws_size,
                              hipStream_t stream) {
    const float* x      = (const float*)d_in[0];   // (B, C, T) f32
    const float* codes  = (const float*)d_in[1];   // (C, K)    f32
    const float* scales = (const float*)d_in[2];   // (K)       f32
    float* out  = (float*)d_out;                   // (B, K, C) f32
    float* w_ws = (float*)d_ws;                    // (B, K, T) = 2.048 MB scratch

    lde_weights<<<Bn * 32, 256, 0, stream>>>(x, codes, scales, w_ws);
    lde_pool<<<Bn * 16, 256, 0, stream>>>(x, codes, w_ws, out);
}

// Round 2
// 105.142 us; speedup vs baseline: 1.3193x; 1.3193x over previous
//
#include <hip/hip_runtime.h>

// Problem constants: B=8, C=256, K=64, T=1000
constexpr int Bn = 8;
constexpr int Cn = 256;
constexpr int Kn = 64;
constexpr int Tn = 1000;

// ---------------------------------------------------------------------------
// Kernel A: weights. One wave (64 threads) per (b, t-quad). lane = k.
//   r2[k,t] = sum_c (x[b,c,t] - codes[c,k])^2 ; w = softmax_k(-scales[k]*r2)
// x[b,c,t..t+3] is wave-uniform -> scalar loads (s_load_dwordx4).
// codes[c,:] is a coalesced 256B vector load (64KB, stays L1/L2 hot).
// No LDS. Grid = 8*250 = 2000 blocks.
// ---------------------------------------------------------------------------
__global__ __launch_bounds__(64) void lde_weights(
    const float* __restrict__ x,       // (B, C, T)
    const float* __restrict__ codes,   // (C, K)
    const float* __restrict__ scales,  // (K)
    float* __restrict__ w_out)         // (B, K, T)
{
    const int lane = threadIdx.x;          // = k
    const int q    = blockIdx.x;           // 0..1999
    const int b    = q / 250;
    const int t0   = (q % 250) * 4;

    const float* xp = x + (size_t)b * Cn * Tn + t0;

    float a0 = 0.f, a1 = 0.f, a2 = 0.f, a3 = 0.f;
#pragma unroll 4
    for (int c = 0; c < Cn; ++c) {
        float  av = codes[c * Kn + lane];            // coalesced vector load
        float4 xv = *(const float4*)(xp + c * Tn);   // wave-uniform -> s_load
        float d;
        d = xv.x - av; a0 = fmaf(d, d, a0);
        d = xv.y - av; a1 = fmaf(d, d, a1);
        d = xv.z - av; a2 = fmaf(d, d, a2);
        d = xv.w - av; a3 = fmaf(d, d, a3);
    }

    const float sc = scales[lane];
    float l0 = -sc * a0, l1 = -sc * a1, l2 = -sc * a2, l3 = -sc * a3;

    // softmax over k (= lanes), 4 independent t's
    float m0 = l0, m1 = l1, m2 = l2, m3 = l3;
#pragma unroll
    for (int off = 32; off >= 1; off >>= 1) {
        m0 = fmaxf(m0, __shfl_xor(m0, off, 64));
        m1 = fmaxf(m1, __shfl_xor(m1, off, 64));
        m2 = fmaxf(m2, __shfl_xor(m2, off, 64));
        m3 = fmaxf(m3, __shfl_xor(m3, off, 64));
    }
    float e0 = __expf(l0 - m0), e1 = __expf(l1 - m1);
    float e2 = __expf(l2 - m2), e3 = __expf(l3 - m3);
    float s0 = e0, s1 = e1, s2 = e2, s3 = e3;
#pragma unroll
    for (int off = 32; off >= 1; off >>= 1) {
        s0 += __shfl_xor(s0, off, 64);
        s1 += __shfl_xor(s1, off, 64);
        s2 += __shfl_xor(s2, off, 64);
        s3 += __shfl_xor(s3, off, 64);
    }

    float4 wq = make_float4(e0 / s0, e1 / s1, e2 / s2, e3 / s3);
    *(float4*)(w_out + (size_t)(b * Kn + lane) * Tn + t0) = wq;   // 16B own-row store
}

// ---------------------------------------------------------------------------
// Kernel B: Xw partials. Block = (b, k-range of 16, t-chunk of 64).
//   part[b,kh,ch,kk,c] = sum_{t in chunk} w[b,k0+kk,t] * x[b,c,t]
// Thread = c. w reads are wave-uniform -> s_load_dwordx4, used as the scalar
// operand of v_fmac (1 SGPR operand allowed). x is per-lane float4 with full
// 64B-line reuse across successive t-quads (L1-resident working set).
// Grid = 8*4*16 = 512 blocks.
// ---------------------------------------------------------------------------
__global__ __launch_bounds__(256) void lde_dotp(
    const float* __restrict__ x,       // (B, C, T)
    const float* __restrict__ w,       // (B, K, T)
    float* __restrict__ part)          // (B, 4, 16, 16, 256)
{
    const int bid = blockIdx.x;
    const int b   = bid >> 6;
    const int kh  = (bid >> 4) & 3;
    const int ch  = bid & 15;
    const int k0  = kh * 16;
    const int t0  = ch * 64;
    const int c   = threadIdx.x;

    const float* xr = x + (size_t)(b * Cn + c) * Tn;
    const float* wr = w + (size_t)(b * Kn + k0) * Tn;

    float acc[16];
#pragma unroll
    for (int kk = 0; kk < 16; ++kk) acc[kk] = 0.f;

    const int tEnd = (t0 + 64 < Tn) ? (t0 + 64) : Tn;
    for (int t = t0; t < tEnd; t += 4) {
        float4 xv = *(const float4*)(xr + t);
#pragma unroll
        for (int kk = 0; kk < 16; ++kk) {
            float4 wv = *(const float4*)(wr + kk * Tn + t);  // uniform -> s_load
            float a = acc[kk];
            a = fmaf(xv.x, wv.x, a);
            a = fmaf(xv.y, wv.y, a);
            a = fmaf(xv.z, wv.z, a);
            a = fmaf(xv.w, wv.w, a);
            acc[kk] = a;
        }
    }

    float* pp = part + (size_t)((b * 4 + kh) * 16 + ch) * (16 * 256);
#pragma unroll
    for (int kk = 0; kk < 16; ++kk)
        pp[kk * 256 + c] = acc[kk];    // coalesced 1KB rows
}

// ---------------------------------------------------------------------------
// Kernel R: reduce partials + codes correction + L2 normalize.
// Block per (b,k) = 512 blocks, thread = c.
// ---------------------------------------------------------------------------
__global__ __launch_bounds__(256) void lde_finish(
    const float* __restrict__ part,    // (B, 4, 16, 16, 256)
    const float* __restrict__ w,       // (B, K, T)
    const float* __restrict__ codes,   // (C, K)
    float* __restrict__ out)           // (B, K, C)
{
    const int bid  = blockIdx.x;
    const int b    = bid >> 6;
    const int k    = bid & 63;
    const int tid  = threadIdx.x;
    const int lane = tid & 63;
    const int wv   = tid >> 6;

    __shared__ float red[4];

    // S = sum_t w[b,k,t]
    const float* wr = w + (size_t)(b * Kn + k) * Tn;
    float s = 0.f;
    for (int t = tid; t < Tn; t += 256) s += wr[t];
#pragma unroll
    for (int off = 32; off >= 1; off >>= 1) s += __shfl_xor(s, off, 64);
    if (lane == 0) red[wv] = s;
    __syncthreads();
    const float S = red[0] + red[1] + red[2] + red[3];
    __syncthreads();

    const int c  = tid;
    const int kh = k >> 4, kk = k & 15;
    const float* pp = part + (size_t)((b * 4 + kh) * 16) * (16 * 256) + kk * 256 + c;
    float val = 0.f;
#pragma unroll
    for (int chk = 0; chk < 16; ++chk) val += pp[chk * (16 * 256)];

    float e = (val - codes[c * Kn + k] * S) * (1.0f / (float)Tn);

    float q2 = e * e;
#pragma unroll
    for (int off = 32; off >= 1; off >>= 1) q2 += __shfl_xor(q2, off, 64);
    if (lane == 0) red[wv] = q2;
    __syncthreads();
    float n = sqrtf(red[0] + red[1] + red[2] + red[3]);

    out[(size_t)(b * Kn + k) * Cn + c] = e / fmaxf(n, 1e-12f);
}

extern "C" void kernel_launch(void* const* d_in, const int* in_sizes, int n_in,
                              void* d_out, int out_size, void* d_ws, size_t ws_size,
                              hipStream_t stream) {
    const float* x      = (const float*)d_in[0];   // (B, C, T) f32
    const float* codes  = (const float*)d_in[1];   // (C, K)    f32
    const float* scales = (const float*)d_in[2];   // (K)       f32
    float* out  = (float*)d_out;                   // (B, K, C) f32

    float* w_ws  = (float*)d_ws;                   // 512000 f = 2.048 MB
    float* part  = (float*)d_ws + (1 << 19);       // 8*4*16*16*256 = 2,097,152 f = 8 MiB

    lde_weights<<<Bn * 250, 64,  0, stream>>>(x, codes, scales, w_ws);
    lde_dotp   <<<Bn * 64,  256, 0, stream>>>(x, w_ws, part);
    lde_finish <<<Bn * 64,  256, 0, stream>>>(part, w_ws, codes, out);
}

// Round 3
// 97.635 us; speedup vs baseline: 1.4207x; 1.0769x over previous
//
#include <hip/hip_runtime.h>

// Problem constants: B=8, C=256, K=64, T=1000
constexpr int Bn  = 8;
constexpr int Cn  = 256;
constexpr int Kn  = 64;
constexpr int Tn  = 1000;
constexpr int CH  = 32;   // t-chunk per block
constexpr int NCH = 32;   // ceil(1000/32)

// ---------------------------------------------------------------------------
// Fused kernel: per (b, t-chunk of 32):
//   phase 1: M[k,t] = sum_c codes[c,k] * x[b,c,t]   (register-tiled GEMM)
//            r2[k,t] = xsq[t] - 2*M + csq[k]
//   softmax: w[k,t] = softmax_k(-scales[k] * r2[k,t])  -> LDS
//   phase 2: part[b,ch,k,c] = sum_{t in chunk} x[b,c,t] * w[k,t]
//            Sp[b,ch,k]     = sum_{t in chunk} w[k,t]
// Grid 8*32 = 256 blocks, 256 threads (4 waves). LDS ~45 KB.
// ---------------------------------------------------------------------------
__global__ __launch_bounds__(256) void lde_ab(
    const float* __restrict__ x,       // (B, C, T)
    const float* __restrict__ codes,   // (C, K)
    const float* __restrict__ scales,  // (K)
    float* __restrict__ part,          // (B, NCH, K, C)
    float* __restrict__ Sp)            // (B, NCH, K)
{
    __shared__ float xs[Cn * 33];      // x[c][t], pad 33: bank (c+t)%32, conflict-free
    __shared__ float ws[Kn * 36];      // M then w, pad 36: 16B-aligned rows for b128
    __shared__ float xsq[CH];          // sum_c x^2 per t
    __shared__ float cpart[4 * 64];    // csq partials
    __shared__ float spw[4 * 64];      // S partials per wave

    const int tid  = threadIdx.x;
    const int wave = tid >> 6;
    const int lane = tid & 63;
    const int b    = blockIdx.x >> 5;
    const int ch   = blockIdx.x & 31;
    const int t0   = ch * CH;

    // --- csq partials: thread (w4 = tid>>6, k = tid&63) covers c = 4r + w4 ---
    {
        const int k = tid & 63, w4 = tid >> 6;
        float a = 0.f;
#pragma unroll 8
        for (int r = 0; r < 64; ++r) {
            float v = codes[(r * 4 + w4) * Kn + k];   // per-wave contiguous 256B
            a = fmaf(v, v, a);
        }
        cpart[w4 * 64 + k] = a;
    }

    // --- stage x chunk into LDS (zero-padded past T) ---
    {
        const float* xb = x + (size_t)b * Cn * Tn;
#pragma unroll
        for (int r = 0; r < 8; ++r) {
            int idx = r * 256 + tid;
            int c = idx >> 3, q = idx & 7;
            int t = t0 + 4 * q;
            float4 v;
            if (t + 3 < Tn) {
                v = *(const float4*)(xb + c * Tn + t);
            } else {
                v.x = (t     < Tn) ? xb[c * Tn + t]     : 0.f;
                v.y = (t + 1 < Tn) ? xb[c * Tn + t + 1] : 0.f;
                v.z = (t + 2 < Tn) ? xb[c * Tn + t + 2] : 0.f;
                v.w = (t + 3 < Tn) ? xb[c * Tn + t + 3] : 0.f;
            }
            float* d = xs + c * 33 + 4 * q;
            d[0] = v.x; d[1] = v.y; d[2] = v.z; d[3] = v.w;
        }
    }
    __syncthreads();

    // --- phase 1: M[k,t] GEMM. lane = (kp, t); wave owns 16 k (8 per kp). ---
    {
        const int kp = lane >> 5;
        const int t  = lane & 31;
        const int kbase = wave * 16 + kp * 8;
        const float* cb = codes + kbase;
        float m[8] = {0, 0, 0, 0, 0, 0, 0, 0};
        float xa = 0.f;
#pragma unroll 4
        for (int c = 0; c < Cn; ++c) {
            float4 c0 = *(const float4*)(cb + c * Kn);       // broadcast (2 addrs/wave)
            float4 c1 = *(const float4*)(cb + c * Kn + 4);
            float  xv = xs[c * 33 + t];                      // 2-way (free)
            m[0] = fmaf(c0.x, xv, m[0]); m[1] = fmaf(c0.y, xv, m[1]);
            m[2] = fmaf(c0.z, xv, m[2]); m[3] = fmaf(c0.w, xv, m[3]);
            m[4] = fmaf(c1.x, xv, m[4]); m[5] = fmaf(c1.y, xv, m[5]);
            m[6] = fmaf(c1.z, xv, m[6]); m[7] = fmaf(c1.w, xv, m[7]);
            xa   = fmaf(xv, xv, xa);
        }
#pragma unroll
        for (int i = 0; i < 8; ++i) ws[(kbase + i) * 36 + t] = m[i];
        if (tid < 32) xsq[t] = xa;    // wave0, kp==0
    }
    __syncthreads();

    // --- softmax over k: wave handles t-oct wave*8..+7, lane = k ---
    {
        const float sc  = scales[lane];
        const float csq = cpart[lane] + cpart[64 + lane] + cpart[128 + lane] + cpart[192 + lane];
        float sp = 0.f;
#pragma unroll
        for (int j = 0; j < 8; ++j) {
            int t = wave * 8 + j;
            float mkt   = ws[lane * 36 + t];
            float logit = -sc * (xsq[t] - 2.f * mkt + csq);
            float mx = logit;
#pragma unroll
            for (int off = 32; off >= 1; off >>= 1)
                mx = fmaxf(mx, __shfl_xor(mx, off, 64));
            float e = __expf(logit - mx);
            float s = e;
#pragma unroll
            for (int off = 32; off >= 1; off >>= 1)
                s += __shfl_xor(s, off, 64);
            float wv = e * __builtin_amdgcn_rcpf(s);
            if (t0 + t >= Tn) wv = 0.f;    // kill padded t
            sp += wv;
            ws[lane * 36 + t] = wv;
        }
        spw[wave * 64 + lane] = sp;
    }
    __syncthreads();

    if (wave == 0) {
        float s4 = spw[lane] + spw[64 + lane] + spw[128 + lane] + spw[192 + lane];
        Sp[(b * NCH + ch) * Kn + lane] = s4;
    }

    // --- phase 2: outer product. wave -> 16 k; thread -> 4 c (lane + 64*cc) ---
    {
        const int k0 = wave * 16;
        float acc[4][16];
#pragma unroll
        for (int cc = 0; cc < 4; ++cc)
#pragma unroll
            for (int kk = 0; kk < 16; ++kk) acc[cc][kk] = 0.f;

#pragma unroll 2
        for (int q = 0; q < 8; ++q) {
            float xv[4][4];
#pragma unroll
            for (int cc = 0; cc < 4; ++cc) {
                const float* xp = xs + (lane + 64 * cc) * 33 + 4 * q;
                xv[cc][0] = xp[0]; xv[cc][1] = xp[1];
                xv[cc][2] = xp[2]; xv[cc][3] = xp[3];
            }
#pragma unroll
            for (int kk = 0; kk < 16; ++kk) {
                float4 wq = *(const float4*)(ws + (k0 + kk) * 36 + 4 * q);  // broadcast
#pragma unroll
                for (int cc = 0; cc < 4; ++cc) {
                    float a = acc[cc][kk];
                    a = fmaf(xv[cc][0], wq.x, a);
                    a = fmaf(xv[cc][1], wq.y, a);
                    a = fmaf(xv[cc][2], wq.z, a);
                    a = fmaf(xv[cc][3], wq.w, a);
                    acc[cc][kk] = a;
                }
            }
        }

        float* pb = part + ((size_t)(b * NCH + ch) * Kn + k0) * Cn + lane;
#pragma unroll
        for (int kk = 0; kk < 16; ++kk)
#pragma unroll
            for (int cc = 0; cc < 4; ++cc)
                pb[kk * Cn + 64 * cc] = acc[cc][kk];    // 256B coalesced per store
    }
}

// ---------------------------------------------------------------------------
// Finish: per (b,k) block (512 blocks, 256 threads = c).
//   val[c] = sum_ch part ;  e = (val - codes[c,k]*S)/T ;  out = e/max(||e||,eps)
// ---------------------------------------------------------------------------
__global__ __launch_bounds__(256) void lde_finish(
    const float* __restrict__ part,    // (B, NCH, K, C)
    const float* __restrict__ Sp,      // (B, NCH, K)
    const float* __restrict__ codes,   // (C, K)
    float* __restrict__ out)           // (B, K, C)
{
    const int b    = blockIdx.x >> 6;
    const int k    = blockIdx.x & 63;
    const int tid  = threadIdx.x;
    const int lane = tid & 63;
    const int wave = tid >> 6;

    __shared__ float red[4];

    // S = sum_ch Sp[b,ch,k] (each thread reads ch = tid&31, reduce over 32)
    float s = Sp[(b * NCH + (tid & 31)) * Kn + k];
#pragma unroll
    for (int off = 16; off >= 1; off >>= 1) s += __shfl_xor(s, off, 64);

    const int c = tid;
    const float* pb = part + (size_t)b * NCH * Kn * Cn + k * Cn + c;
    float val = 0.f;
#pragma unroll
    for (int chk = 0; chk < NCH; ++chk) val += pb[(size_t)chk * Kn * Cn];

    float e = (val - codes[c * Kn + k] * s) * (1.0f / (float)Tn);

    float q = e * e;
#pragma unroll
    for (int off = 32; off >= 1; off >>= 1) q += __shfl_xor(q, off, 64);
    if (lane == 0) red[wave] = q;
    __syncthreads();
    float n = sqrtf(red[0] + red[1] + red[2] + red[3]);

    out[(size_t)(b * Kn + k) * Cn + c] = e * __builtin_amdgcn_rcpf(fmaxf(n, 1e-12f));
}

extern "C" void kernel_launch(void* const* d_in, const int* in_sizes, int n_in,
                              void* d_out, int out_size, void* d_ws, size_t ws_size,
                              hipStream_t stream) {
    const float* x      = (const float*)d_in[0];   // (B, C, T) f32
    const float* codes  = (const float*)d_in[1];   // (C, K)    f32
    const float* scales = (const float*)d_in[2];   // (K)       f32
    float* out = (float*)d_out;                    // (B, K, C) f32

    float* part = (float*)d_ws;                             // 16.78 MB
    float* Sp   = (float*)d_ws + (size_t)Bn * NCH * Kn * Cn; // 64 KB

    lde_ab    <<<Bn * NCH, 256, 0, stream>>>(x, codes, scales, part, Sp);
    lde_finish<<<Bn * Kn,  256, 0, stream>>>(part, Sp, codes, out);
}

// Round 4
// 84.030 us; speedup vs baseline: 1.6507x; 1.1619x over previous
//
#include <hip/hip_runtime.h>

// Problem constants: B=8, C=256, K=64, T=1000
constexpr int Bn  = 8;
constexpr int Cn  = 256;
constexpr int Kn  = 64;
constexpr int Tn  = 1000;
constexpr int CH  = 32;   // t-chunk per block
constexpr int NCH = 32;   // chunks per b

// ---------------------------------------------------------------------------
// Fused kernel, one block per (b, t-chunk of 32), 512 threads = 8 waves
// (2 waves/SIMD for latency hiding; 1 block/CU).
//   stage:   x chunk (256c x 32t) and codes (256x64) into LDS
//   phase 1: M[k,t] = sum_c codes[c,k]*x[c,t]; wave w owns k = 8w..8w+7,
//            lane = (kp, t): kp selects k-quad, t = lane&31. All operands LDS.
//   softmax: w[k,t] = softmax_k(-scales[k]*(xsq[t] - 2M + csq[k])) -> LDS
//   phase 2: part[b,k,ch,c] = sum_t x[c,t]*w[k,t]; Sp[b,k,ch] = sum_t w[k,t]
// ---------------------------------------------------------------------------
__global__ __launch_bounds__(512) void lde_ab(
    const float* __restrict__ x,       // (B, C, T)
    const float* __restrict__ codes,   // (C, K)
    const float* __restrict__ scales,  // (K)
    float* __restrict__ part,          // (B, K, NCH, C)
    float* __restrict__ Sp)            // (B, K, NCH)
{
    __shared__ float xs[Cn * 33];      // x[c][t], pad 33 -> bank (c+t)%32
    __shared__ float cds[Cn * 64];     // codes[c][k], natural layout
    __shared__ float ws[Kn * 36];      // M then w, pad 36 (16B-aligned rows)
    __shared__ float xsq[CH];          // sum_c x^2 per t
    __shared__ float cpw[8 * 64];      // csq partials per wave
    __shared__ float spw[8 * 64];      // S partials per wave

    const int tid  = threadIdx.x;
    const int wave = tid >> 6;
    const int lane = tid & 63;
    const int b    = blockIdx.x >> 5;
    const int ch   = blockIdx.x & 31;
    const int t0   = ch * CH;

    // --- stage codes: 16384 floats = 4096 float4, 8 per thread, coalesced ---
    {
        const float4* cg = (const float4*)codes;
        float4*       cd = (float4*)cds;
#pragma unroll
        for (int r = 0; r < 8; ++r) cd[r * 512 + tid] = cg[r * 512 + tid];
    }

    // --- stage x chunk: 2048 float4, 4 per thread, zero-padded past T ---
    {
        const float* xb = x + (size_t)b * Cn * Tn;
#pragma unroll
        for (int r = 0; r < 4; ++r) {
            int idx = r * 512 + tid;
            int c = idx >> 3, q = idx & 7;
            int t = t0 + 4 * q;
            float4 v;
            if (t + 3 < Tn) {
                v = *(const float4*)(xb + c * Tn + t);
            } else {
                v.x = (t     < Tn) ? xb[c * Tn + t]     : 0.f;
                v.y = (t + 1 < Tn) ? xb[c * Tn + t + 1] : 0.f;
                v.z = (t + 2 < Tn) ? xb[c * Tn + t + 2] : 0.f;
                v.w = (t + 3 < Tn) ? xb[c * Tn + t + 3] : 0.f;
            }
            float* d = xs + c * 33 + 4 * q;
            d[0] = v.x; d[1] = v.y; d[2] = v.z; d[3] = v.w;
        }
    }
    __syncthreads();

    // --- csq partials: wave w covers c = 32w..32w+31, lane = k ---
    {
        float cs = 0.f;
#pragma unroll 8
        for (int j = 0; j < 32; ++j) {
            float v = cds[(wave * 32 + j) * 64 + lane];   // 2-way (free)
            cs = fmaf(v, v, cs);
        }
        cpw[wave * 64 + lane] = cs;
    }

    // --- phase 1: wave w -> k = 8w..8w+7; lane = (kp, t) ---
    {
        const int kp    = lane >> 5;
        const int t     = lane & 31;
        const int kbase = wave * 8 + kp * 4;
        float m0 = 0.f, m1 = 0.f, m2 = 0.f, m3 = 0.f, xa = 0.f;
#pragma unroll 4
        for (int c = 0; c < Cn; ++c) {
            float4 cv = *(const float4*)(cds + c * 64 + kbase);  // 2-addr broadcast b128
            float  xv = xs[c * 33 + t];                          // 2-way (free)
            m0 = fmaf(cv.x, xv, m0);
            m1 = fmaf(cv.y, xv, m1);
            m2 = fmaf(cv.z, xv, m2);
            m3 = fmaf(cv.w, xv, m3);
            xa = fmaf(xv, xv, xa);
        }
        ws[(kbase + 0) * 36 + t] = m0;
        ws[(kbase + 1) * 36 + t] = m1;
        ws[(kbase + 2) * 36 + t] = m2;
        ws[(kbase + 3) * 36 + t] = m3;
        if (tid < 32) xsq[tid] = xa;   // wave 0, kp==0
    }
    __syncthreads();

    // --- softmax over k (lanes); wave w handles t = 4w..4w+3 ---
    {
        const float sc  = scales[lane];
        float csq = 0.f;
#pragma unroll
        for (int w = 0; w < 8; ++w) csq += cpw[w * 64 + lane];
        float sp = 0.f;
#pragma unroll
        for (int j = 0; j < 4; ++j) {
            int t = wave * 4 + j;
            float mkt   = ws[lane * 36 + t];
            float logit = -sc * (xsq[t] - 2.f * mkt + csq);
            float mx = logit;
#pragma unroll
            for (int off = 32; off >= 1; off >>= 1)
                mx = fmaxf(mx, __shfl_xor(mx, off, 64));
            float e = __expf(logit - mx);
            float s = e;
#pragma unroll
            for (int off = 32; off >= 1; off >>= 1)
                s += __shfl_xor(s, off, 64);
            float wv = e * __builtin_amdgcn_rcpf(s);
            if (t0 + t >= Tn) wv = 0.f;     // kill padded t
            sp += wv;
            ws[lane * 36 + t] = wv;
        }
        spw[wave * 64 + lane] = sp;
    }
    __syncthreads();

    if (wave == 0) {
        float s8 = 0.f;
#pragma unroll
        for (int w = 0; w < 8; ++w) s8 += spw[w * 64 + lane];
        Sp[((size_t)b * Kn + lane) * NCH + ch] = s8;
    }

    // --- phase 2: wave w -> k = 8w..8w+7; thread -> c = lane + 64*cc ---
    {
        const int k0 = wave * 8;
        float acc[4][8];
#pragma unroll
        for (int cc = 0; cc < 4; ++cc)
#pragma unroll
            for (int kk = 0; kk < 8; ++kk) acc[cc][kk] = 0.f;

#pragma unroll 2
        for (int q = 0; q < 8; ++q) {
            float xv[4][4];
#pragma unroll
            for (int cc = 0; cc < 4; ++cc) {
                const float* xp = xs + (lane + 64 * cc) * 33 + 4 * q;
                xv[cc][0] = xp[0]; xv[cc][1] = xp[1];
                xv[cc][2] = xp[2]; xv[cc][3] = xp[3];
            }
#pragma unroll
            for (int kk = 0; kk < 8; ++kk) {
                float4 wq = *(const float4*)(ws + (k0 + kk) * 36 + 4 * q);  // broadcast
#pragma unroll
                for (int cc = 0; cc < 4; ++cc) {
                    float a = acc[cc][kk];
                    a = fmaf(xv[cc][0], wq.x, a);
                    a = fmaf(xv[cc][1], wq.y, a);
                    a = fmaf(xv[cc][2], wq.z, a);
                    a = fmaf(xv[cc][3], wq.w, a);
                    acc[cc][kk] = a;
                }
            }
        }

        // part[b, k, ch, c]: 256B-coalesced stores
#pragma unroll
        for (int kk = 0; kk < 8; ++kk) {
            float* pb = part + (((size_t)b * Kn + k0 + kk) * NCH + ch) * Cn + lane;
#pragma unroll
            for (int cc = 0; cc < 4; ++cc)
                pb[64 * cc] = acc[cc][kk];
        }
    }
}

// ---------------------------------------------------------------------------
// Finish: block per (b,k) (512 blocks, 256 thr = c). Contiguous 32KB stream.
// ---------------------------------------------------------------------------
__global__ __launch_bounds__(256) void lde_finish(
    const float* __restrict__ part,    // (B, K, NCH, C)
    const float* __restrict__ Sp,      // (B, K, NCH)
    const float* __restrict__ codes,   // (C, K)
    float* __restrict__ out)           // (B, K, C)
{
    const int b    = blockIdx.x >> 6;
    const int k    = blockIdx.x & 63;
    const int tid  = threadIdx.x;
    const int lane = tid & 63;
    const int wave = tid >> 6;

    __shared__ float red[4];

    // S = sum_ch Sp[b,k,ch]; lanes 0..31 read contiguous 128B, halves duplicate
    float s = Sp[((size_t)b * Kn + k) * NCH + (tid & 31)];
#pragma unroll
    for (int off = 16; off >= 1; off >>= 1) s += __shfl_xor(s, off, 64);

    const int c = tid;
    const float* pb = part + ((size_t)b * Kn + k) * NCH * Cn + c;
    float val = 0.f;
#pragma unroll
    for (int chk = 0; chk < NCH; ++chk) val += pb[chk * Cn];

    float e = (val - codes[c * Kn + k] * s) * (1.0f / (float)Tn);

    float q = e * e;
#pragma unroll
    for (int off = 32; off >= 1; off >>= 1) q += __shfl_xor(q, off, 64);
    if (lane == 0) red[wave] = q;
    __syncthreads();
    float n = sqrtf(red[0] + red[1] + red[2] + red[3]);

    out[((size_t)b * Kn + k) * Cn + c] = e * __builtin_amdgcn_rcpf(fmaxf(n, 1e-12f));
}

extern "C" void kernel_launch(void* const* d_in, const int* in_sizes, int n_in,
                              void* d_out, int out_size, void* d_ws, size_t ws_size,
                              hipStream_t stream) {
    const float* x      = (const float*)d_in[0];   // (B, C, T) f32
    const float* codes  = (const float*)d_in[1];   // (C, K)    f32
    const float* scales = (const float*)d_in[2];   // (K)       f32
    float* out = (float*)d_out;                    // (B, K, C) f32

    float* part = (float*)d_ws;                                 // 16.78 MB
    float* Sp   = (float*)d_ws + (size_t)Bn * Kn * NCH * Cn;    // 64 KB

    lde_ab    <<<Bn * NCH, 512, 0, stream>>>(x, codes, scales, part, Sp);
    lde_finish<<<Bn * Kn,  256, 0, stream>>>(part, Sp, codes, out);
}

// Round 5
// 78.057 us; speedup vs baseline: 1.7770x; 1.0765x over previous
//
#include <hip/hip_runtime.h>
#include <stdint.h>

// Problem constants: B=8, C=256, K=64, T=1000
constexpr int Bn  = 8;
constexpr int Cn  = 256;
constexpr int Kn  = 64;
constexpr int Tn  = 1000;
constexpr int CH  = 32;   // t-chunk per block
constexpr int NCH = 32;   // chunks per b

// LDS pitches (ushort elements unless noted). All chosen so that
// (row*pitch + q*8) is a multiple of 8 (16B alignment for b128) and
// bank conflicts stay <=2-way.
constexpr int XC_P = 40;   // xc[c][t]  bf16, 80B rows
constexpr int XT_P = 264;  // xT[t][c]  bf16, 528B rows
constexpr int WA_P = 40;   // wa[k][t]  bf16, 80B rows
constexpr int MW_P = 36;   // Mw[k][t]  f32

typedef float f32x4 __attribute__((ext_vector_type(4)));
typedef __bf16 bf16x8 __attribute__((ext_vector_type(8)));

__device__ __forceinline__ unsigned short f2bf(float f) {
    unsigned u = __float_as_uint(f);
    return (unsigned short)((u + 0x7FFFu + ((u >> 16) & 1u)) >> 16);  // RNE
}

// ---------------------------------------------------------------------------
// Prep (runs every call; ws is re-poisoned each iteration):
//   cT[k][c] = bf16(codes[c][k])   (A-operand layout for phase 1)
//   csq[k]   = sum_c codes[c][k]^2 (fp32 exact)
// Grid: 64 blocks (one per k) x 256 threads (c).
// ---------------------------------------------------------------------------
__global__ __launch_bounds__(256) void lde_prep(
    const float* __restrict__ codes, unsigned short* __restrict__ cT,
    float* __restrict__ csq)
{
    const int k = blockIdx.x, c = threadIdx.x;
    const int lane = c & 63, wv = c >> 6;
    float v = codes[c * Kn + k];
    cT[k * Cn + c] = f2bf(v);
    float q = v * v;
#pragma unroll
    for (int off = 32; off >= 1; off >>= 1) q += __shfl_xor(q, off, 64);
    __shared__ float red[4];
    if (lane == 0) red[wv] = q;
    __syncthreads();
    if (c == 0) csq[k] = red[0] + red[1] + red[2] + red[3];
}

// ---------------------------------------------------------------------------
// Fused weights+pool, MFMA version. One block per (b, t-chunk of 32),
// 512 threads = 8 waves.
//   phase 1 (mfma): M[k,t] = sum_c cT[k][c] * xT[t][c]   (K=256, 8 steps)
//   softmax (fp32): w[k,t] = softmax_k(-scales[k]*(xsq[t] - 2M + csq[k]))
//   phase 2 (mfma): part[b,k,ch,c] = sum_t wa[k][t] * xc[c][t]  (K=32)
// xsq computed from fp32 globals (bf16 there would corrupt logits since
// scales[k] makes the per-t shift non-common-mode).
// ---------------------------------------------------------------------------
union SmemU {
    unsigned short xT[CH * XT_P];   // phase-1 B operand (dead after phase 1)
    unsigned short wa[Kn * WA_P];   // softmax output / phase-2 A operand
};

__global__ __launch_bounds__(512) void lde_ab(
    const float* __restrict__ x,            // (B, C, T)
    const unsigned short* __restrict__ cT,  // (K, C) bf16
    const float* __restrict__ csq_g,        // (K)
    const float* __restrict__ scales,       // (K)
    float* __restrict__ part,               // (B, K, NCH, C)
    float* __restrict__ Sp)                 // (B, K, NCH)
{
    __shared__ __align__(16) unsigned short xc[Cn * XC_P];  // x bf16 [c][t]
    __shared__ __align__(16) SmemU u;
    __shared__ float Mw[Kn * MW_P];
    __shared__ float xsqp[16 * 33];
    __shared__ float xsq[CH];
    __shared__ float spw[8 * 64];

    const int tid  = threadIdx.x;
    const int wave = tid >> 6;
    const int lane = tid & 63;
    const int b    = blockIdx.x >> 5;
    const int ch   = blockIdx.x & 31;
    const int t0   = ch * CH;
    const int n    = lane & 15;
    const int q    = lane >> 4;
    const float* xb = x + (size_t)b * Cn * Tn;

    // --- 1) stage xc: global float4 -> bf16, t-contiguous rows ---
#pragma unroll
    for (int r = 0; r < 4; ++r) {
        int idx = r * 512 + tid;
        int c = idx >> 3, qq = idx & 7;
        int t = t0 + 4 * qq;
        float4 v;
        if (t + 3 < Tn) {
            v = *(const float4*)(xb + c * Tn + t);
        } else {
            v.x = (t     < Tn) ? xb[c * Tn + t]     : 0.f;
            v.y = (t + 1 < Tn) ? xb[c * Tn + t + 1] : 0.f;
            v.z = (t + 2 < Tn) ? xb[c * Tn + t + 2] : 0.f;
            v.w = (t + 3 < Tn) ? xb[c * Tn + t + 3] : 0.f;
        }
        *(ushort4*)(xc + c * XC_P + 4 * qq) =
            make_ushort4(f2bf(v.x), f2bf(v.y), f2bf(v.z), f2bf(v.w));
    }

    // --- 2) xsq partials from fp32 global (exactness required) ---
    {
        int tl = tid & 31, s = tid >> 5;   // s in 0..15, 16 c's each
        float a = 0.f;
        if (t0 + tl < Tn) {
            const float* xp = xb + (s * 16) * Tn + t0 + tl;
#pragma unroll
            for (int i = 0; i < 16; ++i) {
                float v = xp[i * Tn];
                a = fmaf(v, v, a);
            }
        }
        xsqp[s * 33 + tl] = a;
    }
    __syncthreads();

    // --- 3) build xT (c-contiguous bf16) from xc; reduce xsq ---
#pragma unroll
    for (int r = 0; r < 2; ++r) {
        int idx = r * 512 + tid;
        int t = idx & 31, cg = idx >> 5;
        unsigned short tmp[8];
#pragma unroll
        for (int i = 0; i < 8; ++i) tmp[i] = xc[(cg * 8 + i) * XC_P + t];
        *(ushort4*)(u.xT + t * XT_P + cg * 8)     = make_ushort4(tmp[0], tmp[1], tmp[2], tmp[3]);
        *(ushort4*)(u.xT + t * XT_P + cg * 8 + 4) = make_ushort4(tmp[4], tmp[5], tmp[6], tmp[7]);
    }
    if (tid < CH) {
        float a = 0.f;
#pragma unroll
        for (int s = 0; s < 16; ++s) a += xsqp[s * 33 + tid];
        xsq[tid] = a;
    }
    __syncthreads();

    // --- 4) phase 1 MFMA: wave = (kt 0..3, tt 0..1) -> 16k x 16t tile ---
    {
        const int kt = wave & 3, tt = wave >> 2;
        const int k = kt * 16 + n;     // A: m = lane&15
        const int t = tt * 16 + n;     // B: n = lane&15
        f32x4 acc = {0.f, 0.f, 0.f, 0.f};
        const unsigned short* Ab = cT + k * Cn + q * 8;     // global, L2-hot
        const unsigned short* Bb = u.xT + t * XT_P + q * 8; // LDS
#pragma unroll
        for (int c0 = 0; c0 < Cn; c0 += 32) {
            bf16x8 aF = *(const bf16x8*)(Ab + c0);
            bf16x8 bF = *(const bf16x8*)(Bb + c0);
            acc = __builtin_amdgcn_mfma_f32_16x16x32_bf16(aF, bF, acc, 0, 0, 0);
        }
        // D: col = n -> t, row = q*4+r -> k
#pragma unroll
        for (int r = 0; r < 4; ++r)
            Mw[(kt * 16 + q * 4 + r) * MW_P + tt * 16 + n] = acc[r];
    }
    __syncthreads();

    // --- 5) softmax over k (lane = k); wave handles t = 4*wave..+3 ---
    {
        const float sc = scales[lane];
        const float cq = csq_g[lane];
        unsigned short wh[4];
        float sp = 0.f;
#pragma unroll
        for (int j = 0; j < 4; ++j) {
            int t = wave * 4 + j;
            float m     = Mw[lane * MW_P + t];
            float logit = -sc * (xsq[t] - 2.f * m + cq);
            float mx = logit;
#pragma unroll
            for (int off = 32; off >= 1; off >>= 1)
                mx = fmaxf(mx, __shfl_xor(mx, off, 64));
            float e = __expf(logit - mx);
            float s = e;
#pragma unroll
            for (int off = 32; off >= 1; off >>= 1)
                s += __shfl_xor(s, off, 64);
            float wv = e / s;
            if (t0 + t >= Tn) wv = 0.f;   // padded t contributes nothing
            sp += wv;
            wh[j] = f2bf(wv);
        }
        *(ushort4*)(u.wa + lane * WA_P + wave * 4) =
            make_ushort4(wh[0], wh[1], wh[2], wh[3]);   // xT is dead: safe union
        spw[wave * 64 + lane] = sp;
    }
    __syncthreads();

    // --- 6) Sp + phase 2 MFMA: wave = (kt 0..3, half 0..1) -> 8 c-tiles ---
    if (wave == 0) {
        float s8 = 0.f;
#pragma unroll
        for (int w = 0; w < 8; ++w) s8 += spw[w * 64 + lane];
        Sp[((size_t)b * Kn + lane) * NCH + ch] = s8;
    }
    {
        const int kt = wave & 3, hf = wave >> 2;
        bf16x8 aF = *(const bf16x8*)(u.wa + (kt * 16 + n) * WA_P + q * 8);
#pragma unroll
        for (int i = 0; i < 8; ++i) {
            int c0 = (hf * 8 + i) * 16;
            bf16x8 bF = *(const bf16x8*)(xc + (c0 + n) * XC_P + q * 8);
            f32x4 acc = {0.f, 0.f, 0.f, 0.f};
            acc = __builtin_amdgcn_mfma_f32_16x16x32_bf16(aF, bF, acc, 0, 0, 0);
            // D: col = n -> c, row = q*4+r -> k. 64B-coalesced per store.
            float* pb = part + ((size_t)(b * Kn + kt * 16 + q * 4) * NCH + ch) * Cn + c0 + n;
#pragma unroll
            for (int r = 0; r < 4; ++r)
                pb[(size_t)r * NCH * Cn] = acc[r];
        }
    }
}

// ---------------------------------------------------------------------------
// Finish: block per (b,k) (512 blocks, 256 thr = c). Contiguous 32KB stream.
// ---------------------------------------------------------------------------
__global__ __launch_bounds__(256) void lde_finish(
    const float* __restrict__ part,    // (B, K, NCH, C)
    const float* __restrict__ Sp,      // (B, K, NCH)
    const float* __restrict__ codes,   // (C, K)
    float* __restrict__ out)           // (B, K, C)
{
    const int b    = blockIdx.x >> 6;
    const int k    = blockIdx.x & 63;
    const int tid  = threadIdx.x;
    const int lane = tid & 63;
    const int wave = tid >> 6;

    __shared__ float red[4];

    float s = Sp[((size_t)b * Kn + k) * NCH + (tid & 31)];
#pragma unroll
    for (int off = 16; off >= 1; off >>= 1) s += __shfl_xor(s, off, 64);

    const int c = tid;
    const float* pb = part + ((size_t)b * Kn + k) * NCH * Cn + c;
    float val = 0.f;
#pragma unroll
    for (int chk = 0; chk < NCH; ++chk) val += pb[chk * Cn];

    float e = (val - codes[c * Kn + k] * s) * (1.0f / (float)Tn);

    float qq = e * e;
#pragma unroll
    for (int off = 32; off >= 1; off >>= 1) qq += __shfl_xor(qq, off, 64);
    if (lane == 0) red[wave] = qq;
    __syncthreads();
    float nn = sqrtf(red[0] + red[1] + red[2] + red[3]);

    out[((size_t)b * Kn + k) * Cn + c] = e / fmaxf(nn, 1e-12f);
}

extern "C" void kernel_launch(void* const* d_in, const int* in_sizes, int n_in,
                              void* d_out, int out_size, void* d_ws, size_t ws_size,
                              hipStream_t stream) {
    const float* x      = (const float*)d_in[0];   // (B, C, T) f32
    const float* codes  = (const float*)d_in[1];   // (C, K)    f32
    const float* scales = (const float*)d_in[2];   // (K)       f32
    float* out = (float*)d_out;                    // (B, K, C) f32

    float* part = (float*)d_ws;                                   // 16.78 MB
    float* Sp   = part + (size_t)Bn * Kn * NCH * Cn;              // 64 KB
    float* csq  = Sp + (size_t)Bn * Kn * NCH;                     // 256 B
    unsigned short* cT = (unsigned short*)(csq + 64);             // 32 KB, 16B-aligned

    lde_prep  <<<Kn,       256, 0, stream>>>(codes, cT, csq);
    lde_ab    <<<Bn * NCH, 512, 0, stream>>>(x, cT, csq, scales, part, Sp);
    lde_finish<<<Bn * Kn,  256, 0, stream>>>(part, Sp, codes, out);
}

// Round 6
// 77.626 us; speedup vs baseline: 1.7869x; 1.0055x over previous
//
#include <hip/hip_runtime.h>
#include <stdint.h>

// Problem constants: B=8, C=256, K=64, T=1000
constexpr int Bn  = 8;
constexpr int Cn  = 256;
constexpr int Kn  = 64;
constexpr int Tn  = 1000;
constexpr int CH  = 16;    // K1 t-chunk (T padded to 1024)
constexpr int NCH = 64;    // chunks per b
constexpr int TW  = 256;   // K2 t-window
constexpr int NTQ = 4;     // windows per b

constexpr int XT_P = 264;  // xT[t][c] bf16 pitch (528B rows, 16B-aligned)
constexpr int MW_P = 20;   // Mw[k][t] f32 pitch
constexpr int XC_P = 264;  // K2 xc[c][t] bf16 pitch

typedef float f32x4 __attribute__((ext_vector_type(4)));
typedef __bf16 bf16x8 __attribute__((ext_vector_type(8)));

__device__ __forceinline__ unsigned short f2bf(float f) {
    unsigned u = __float_as_uint(f);
    return (unsigned short)((u + 0x7FFFu + ((u >> 16) & 1u)) >> 16);  // RNE
}

// ---------------------------------------------------------------------------
// Prep: cT[k][c] = bf16(codes[c][k]) (phase-1 A-operand layout),
//       csq[k] = sum_c codes[c][k]^2 (fp32). 64 blocks x 256 thr.
// ---------------------------------------------------------------------------
__global__ __launch_bounds__(256) void lde_prep(
    const float* __restrict__ codes, unsigned short* __restrict__ cT,
    float* __restrict__ csq)
{
    const int k = blockIdx.x, c = threadIdx.x;
    const int lane = c & 63, wv = c >> 6;
    float v = codes[c * Kn + k];
    cT[k * Cn + c] = f2bf(v);            // 512B contiguous per block row
    float q = v * v;
#pragma unroll
    for (int off = 32; off >= 1; off >>= 1) q += __shfl_xor(q, off, 64);
    __shared__ float red[4];
    if (lane == 0) red[wv] = q;
    __syncthreads();
    if (c == 0) csq[k] = red[0] + red[1] + red[2] + red[3];
}

// ---------------------------------------------------------------------------
// K1 weights: grid (b x 64 chunks of 16t) = 512 blocks, 256 thr (4 waves).
//   M[k,t] = sum_c cT[k][c]*xT[t][c] via mfma 16x16x32 (8 K-steps)
//   w[k,t] = softmax_k(-scales[k]*(xsq[t]-2M+csq[k]))  (fp32, xsq from fp32 x)
//   out: w_g (b,ch,k,16) bf16 (contiguous A-frags for K2); Sp (b,k,ch) f32
// t >= 1000 lanes write w=0 so K2 windows read zeros.
// ---------------------------------------------------------------------------
__global__ __launch_bounds__(256) void lde_w(
    const float* __restrict__ x,            // (B, C, T)
    const unsigned short* __restrict__ cT,  // (K, C) bf16
    const float* __restrict__ csq_g,        // (K)
    const float* __restrict__ scales,       // (K)
    unsigned short* __restrict__ w_g,       // (B, NCH, K, CH) bf16
    float* __restrict__ Sp)                 // (B, K, NCH)
{
    __shared__ __align__(16) unsigned short xT[CH * XT_P];  // [t][c]
    __shared__ float Mw[Kn * MW_P];                         // [k][t]
    __shared__ float xsqp[16 * 17];
    __shared__ float xsq[CH];
    __shared__ float spw[4 * 64];

    const int tid  = threadIdx.x;
    const int wave = tid >> 6;
    const int lane = tid & 63;
    const int n    = lane & 15;
    const int q    = lane >> 4;
    const int b    = blockIdx.x >> 6;
    const int ch   = blockIdx.x & 63;
    const int t0   = ch * CH;
    const float* xb = x + (size_t)b * Cn * Tn;

    // --- stage xT directly: thread (c, t-quad), 4 scalar bf16 LDS writes ---
#pragma unroll
    for (int r = 0; r < 4; ++r) {
        int idx = r * 256 + tid;
        int c = idx >> 2, tf = idx & 3;
        int t = t0 + 4 * tf;
        float4 v;
        if (t + 3 < Tn) {
            v = *(const float4*)(xb + c * Tn + t);
        } else {
            v.x = (t     < Tn) ? xb[c * Tn + t]     : 0.f;
            v.y = (t + 1 < Tn) ? xb[c * Tn + t + 1] : 0.f;
            v.z = (t + 2 < Tn) ? xb[c * Tn + t + 2] : 0.f;
            v.w = (t + 3 < Tn) ? xb[c * Tn + t + 3] : 0.f;
        }
        xT[(4 * tf + 0) * XT_P + c] = f2bf(v.x);
        xT[(4 * tf + 1) * XT_P + c] = f2bf(v.y);
        xT[(4 * tf + 2) * XT_P + c] = f2bf(v.z);
        xT[(4 * tf + 3) * XT_P + c] = f2bf(v.w);
    }
    // --- xsq partials from fp32 (L2-hot second read) ---
    {
        int tl = tid & 15, s = tid >> 4;
        float a = 0.f;
        if (t0 + tl < Tn) {
            const float* xp = xb + (s * 16) * Tn + t0 + tl;
#pragma unroll
            for (int i = 0; i < 16; ++i) { float v = xp[i * Tn]; a = fmaf(v, v, a); }
        }
        xsqp[s * 17 + tl] = a;
    }
    __syncthreads();

    if (tid < CH) {
        float a = 0.f;
#pragma unroll
        for (int s = 0; s < 16; ++s) a += xsqp[s * 17 + tid];
        xsq[tid] = a;
    }

    // --- M GEMM: wave = k-tile; A from global cT (L2/L3-hot), B from LDS ---
    {
        const unsigned short* Ab = cT + (wave * 16 + n) * Cn + q * 8;
        const unsigned short* Bb = xT + n * XT_P + q * 8;
        f32x4 acc = {0.f, 0.f, 0.f, 0.f};
#pragma unroll
        for (int c0 = 0; c0 < Cn; c0 += 32) {
            bf16x8 aF = *(const bf16x8*)(Ab + c0);
            bf16x8 bF = *(const bf16x8*)(Bb + c0);
            acc = __builtin_amdgcn_mfma_f32_16x16x32_bf16(aF, bF, acc, 0, 0, 0);
        }
#pragma unroll
        for (int r = 0; r < 4; ++r)
            Mw[(wave * 16 + q * 4 + r) * MW_P + n] = acc[r];   // col n -> t
    }
    __syncthreads();

    // --- softmax over k (lane = k); wave handles t = wave*4..+3 ---
    {
        const float sc = scales[lane];
        const float cq = csq_g[lane];
        unsigned short wh[4];
        float sp = 0.f;
#pragma unroll
        for (int j = 0; j < 4; ++j) {
            int t = wave * 4 + j;
            float m     = Mw[lane * MW_P + t];
            float logit = -sc * (xsq[t] - 2.f * m + cq);
            float mx = logit;
#pragma unroll
            for (int off = 32; off >= 1; off >>= 1)
                mx = fmaxf(mx, __shfl_xor(mx, off, 64));
            float e = __expf(logit - mx);
            float s = e;
#pragma unroll
            for (int off = 32; off >= 1; off >>= 1)
                s += __shfl_xor(s, off, 64);
            float wv = e / s;
            if (t0 + t >= Tn) wv = 0.f;
            sp += wv;
            wh[j] = f2bf(wv);
        }
        *(ushort4*)(w_g + ((size_t)(b * NCH + ch) * Kn + lane) * CH + wave * 4) =
            make_ushort4(wh[0], wh[1], wh[2], wh[3]);
        spw[wave * 64 + lane] = sp;
    }
    __syncthreads();

    if (wave == 0) {
        float s4 = spw[lane] + spw[64 + lane] + spw[128 + lane] + spw[192 + lane];
        Sp[((size_t)b * Kn + lane) * NCH + ch] = s4;
    }
}

// ---------------------------------------------------------------------------
// K2 pool: grid (b x 16 c-tiles x 4 t-windows of 256) = 512 blocks, 4 waves.
//   part[b,tq,k,c] = sum_{t in window} w[k,t] * x[c,t]   (8 mfma / wave)
// ---------------------------------------------------------------------------
__global__ __launch_bounds__(256) void lde_pool(
    const float* __restrict__ x,            // (B, C, T)
    const unsigned short* __restrict__ w_g, // (B, NCH, K, CH) bf16
    float* __restrict__ part)               // (B, NTQ, K, C)
{
    __shared__ __align__(16) unsigned short xc[16 * XC_P];  // [c-local][t-local]

    const int tid  = threadIdx.x;
    const int wave = tid >> 6;            // k-tile
    const int lane = tid & 63;
    const int n    = lane & 15;
    const int q    = lane >> 4;
    const int bid  = blockIdx.x;
    const int b    = bid >> 6;
    const int ct   = (bid >> 2) & 15;
    const int tq   = bid & 3;
    const int c0   = ct * 16;
    const int tw0  = tq * TW;
    const float* xb = x + (size_t)(b * Cn + c0) * Tn;

    // --- stage x tile 16c x 256t -> bf16 LDS ---
#pragma unroll
    for (int r = 0; r < 4; ++r) {
        int idx = r * 256 + tid;
        int cl = idx >> 6, tf = idx & 63;
        int t = tw0 + 4 * tf;
        float4 v;
        if (t + 3 < Tn) {
            v = *(const float4*)(xb + cl * Tn + t);
        } else {
            v.x = (t     < Tn) ? xb[cl * Tn + t]     : 0.f;
            v.y = (t + 1 < Tn) ? xb[cl * Tn + t + 1] : 0.f;
            v.z = (t + 2 < Tn) ? xb[cl * Tn + t + 2] : 0.f;
            v.w = (t + 3 < Tn) ? xb[cl * Tn + t + 3] : 0.f;
        }
        *(ushort4*)(xc + cl * XC_P + 4 * tf) =
            make_ushort4(f2bf(v.x), f2bf(v.y), f2bf(v.z), f2bf(v.w));
    }
    __syncthreads();

    f32x4 acc = {0.f, 0.f, 0.f, 0.f};
#pragma unroll
    for (int s = 0; s < 8; ++s) {
        int tg  = tw0 + s * 32 + q * 8;       // global t of this frag
        int chh = tg >> 4;                    // chunk in w_g
        int tl  = tg & 15;                    // 0 or 8
        bf16x8 aF = *(const bf16x8*)(w_g + ((size_t)(b * NCH + chh) * Kn + wave * 16 + n) * CH + tl);
        bf16x8 bF = *(const bf16x8*)(xc + n * XC_P + s * 32 + q * 8);
        acc = __builtin_amdgcn_mfma_f32_16x16x32_bf16(aF, bF, acc, 0, 0, 0);
    }
    // D: col n -> c, row q*4+r -> k
    float* pb = part + ((size_t)(b * NTQ + tq) * Kn + wave * 16 + q * 4) * Cn + c0 + n;
#pragma unroll
    for (int r = 0; r < 4; ++r)
        pb[(size_t)r * Cn] = acc[r];
}

// ---------------------------------------------------------------------------
// K3 finish: block per (b,k), 256 thr = c.
// ---------------------------------------------------------------------------
__global__ __launch_bounds__(256) void lde_fin(
    const float* __restrict__ part,    // (B, NTQ, K, C)
    const float* __restrict__ Sp,      // (B, K, NCH)
    const float* __restrict__ codes,   // (C, K)
    float* __restrict__ out)           // (B, K, C)
{
    const int b    = blockIdx.x >> 6;
    const int k    = blockIdx.x & 63;
    const int tid  = threadIdx.x;
    const int lane = tid & 63;
    const int wave = tid >> 6;

    __shared__ float red[4];
    __shared__ float Ss;

    if (wave == 0) {
        float s = Sp[((size_t)b * Kn + k) * NCH + lane];   // 256B coalesced
#pragma unroll
        for (int off = 32; off >= 1; off >>= 1) s += __shfl_xor(s, off, 64);
        if (lane == 0) Ss = s;
    }
    __syncthreads();
    const float S = Ss;

    const int c = tid;
    const float* pb = part + (size_t)b * NTQ * Kn * Cn + k * Cn + c;
    float val = pb[0] + pb[(size_t)Kn * Cn] + pb[(size_t)2 * Kn * Cn] + pb[(size_t)3 * Kn * Cn];

    float e = (val - codes[c * Kn + k] * S) * (1.0f / (float)Tn);

    float qq = e * e;
#pragma unroll
    for (int off = 32; off >= 1; off >>= 1) qq += __shfl_xor(qq, off, 64);
    if (lane == 0) red[wave] = qq;
    __syncthreads();
    float nn = sqrtf(red[0] + red[1] + red[2] + red[3]);

    out[((size_t)b * Kn + k) * Cn + c] = e / fmaxf(nn, 1e-12f);
}

extern "C" void kernel_launch(void* const* d_in, const int* in_sizes, int n_in,
                              void* d_out, int out_size, void* d_ws, size_t ws_size,
                              hipStream_t stream) {
    const float* x      = (const float*)d_in[0];   // (B, C, T) f32
    const float* codes  = (const float*)d_in[1];   // (C, K)    f32
    const float* scales = (const float*)d_in[2];   // (K)       f32
    float* out = (float*)d_out;                    // (B, K, C) f32

    char* ws = (char*)d_ws;
    float*          part = (float*)ws;                               // 2 MB
    unsigned short* w_g  = (unsigned short*)(ws + (2u << 20));       // 1 MB
    float*          Sp   = (float*)(ws + (3u << 20));                // 128 KB
    unsigned short* cT   = (unsigned short*)(ws + (3u << 20) + (256u << 10)); // 32 KB
    float*          csq  = (float*)(ws + (3u << 20) + (292u << 10)); // 256 B

    lde_prep<<<Kn,            256, 0, stream>>>(codes, cT, csq);
    lde_w   <<<Bn * NCH,      256, 0, stream>>>(x, cT, csq, scales, w_g, Sp);
    lde_pool<<<Bn * 16 * NTQ, 256, 0, stream>>>(x, w_g, part);
    lde_fin <<<Bn * Kn,       256, 0, stream>>>(part, Sp, codes, out);
}